// Round 1
// baseline (1712.246 us; speedup 1.0000x reference)
//
#include <hip/hip_runtime.h>

// Problem constants
#define BATCH 1024
#define TT 48          // inst columns
#define NSTEP 47       // scan steps
#define VOC 2001       // V+1
#define RNN 64
#define NOBJ 25
#define NROWS (BATCH*NSTEP)   // 48128
#define NTILE 126             // ceil(2016/16)
#define NPAD 2016

typedef _Float16 h2 __attribute__((ext_vector_type(2)));
typedef _Float16 h8 __attribute__((ext_vector_type(8)));
typedef short short8 __attribute__((ext_vector_type(8)));
typedef float f32x4 __attribute__((ext_vector_type(4)));

__device__ __forceinline__ float fdot2f(h2 a, h2 b, float c){
#if __has_builtin(__builtin_amdgcn_fdot2)
    return __builtin_amdgcn_fdot2(a, b, c, false);
#else
    return c + (float)a[0]*(float)b[0] + (float)a[1]*(float)b[1];
#endif
}

__device__ __forceinline__ float sigf(float x){ return 1.f/(1.f+__expf(-x)); }
__device__ __forceinline__ float tanh_(float x){
    float e = __expf(2.f*fminf(x, 15.f));   // clamp avoids inf/inf NaN
    return (e-1.f)/(e+1.f);
}
__device__ __forceinline__ unsigned short bf16r(float f){
    unsigned u = __float_as_uint(f);
    return (unsigned short)((u + 0x7FFFu + ((u>>16)&1u)) >> 16);
}

// ---------------------------------------------------------------- prep kernels

// diff_canvas + time-invariant attention terms pre1/pre2 [B,25,32]
__global__ void k_pre(const float* __restrict__ prev, const float* __restrict__ fin,
                      const float* __restrict__ a1w1, const float* __restrict__ a1b1,
                      const float* __restrict__ a2w1, const float* __restrict__ a2b1,
                      float* __restrict__ diff, float* __restrict__ pre1, float* __restrict__ pre2){
    int idx = blockIdx.x*256 + threadIdx.x;
    if (idx >= BATCH*NOBJ) return;
    float p0 = prev[idx*4+0], p1 = prev[idx*4+1], p2 = prev[idx*4+2], p3 = prev[idx*4+3];
    bool masked = (p0+p1+p2+p3) > 0.f;
    float d0 = masked ? -1.f : fin[idx*4+0];
    float d1 = masked ? -1.f : fin[idx*4+1];
    float d2 = masked ? -1.f : fin[idx*4+2];
    float d3 = masked ? -1.f : fin[idx*4+3];
    diff[idx*4+0]=d0; diff[idx*4+1]=d1; diff[idx*4+2]=d2; diff[idx*4+3]=d3;
    for (int j=0;j<32;++j){
        const float* w1 = a1w1 + j*68 + 64;
        const float* w2 = a2w1 + j*68 + 64;
        pre1[idx*32+j] = a1b1[j] + d0*w1[0] + d1*w1[1] + d2*w1[2] + d3*w1[3];
        pre2[idx*32+j] = a2b1[j] + p0*w2[0] + p1*w2[1] + p2*w2[2] + p3*w2[3];
    }
}

// embW[v][g] = b_ih_att[g]+b_hh_att[g] + sum_k embed[v][k]*W_ih_att[g][64+k]
__global__ void k_embw(const float* __restrict__ embed, const float* __restrict__ Wia,
                       const float* __restrict__ bia, const float* __restrict__ bha,
                       float* __restrict__ embW){
    int v = blockIdx.x, g = threadIdx.x;
    __shared__ float er[64];
    if (g < 64) er[g] = embed[v*64+g];
    __syncthreads();
    float acc = bia[g] + bha[g];
    const float* wr = Wia + g*128 + 64;
    #pragma unroll 8
    for (int k=0;k<64;++k) acc += er[k]*wr[k];
    embW[v*256+g] = acc;
}

// pack fp32 weight [G][srcK] cols koff..koff+K-1 -> f16 layout [k8][G][8]
__global__ void k_packw(const float* __restrict__ src, _Float16* __restrict__ dst,
                        int G, int srcK, int koff, int total){
    int idx = blockIdx.x*256 + threadIdx.x;
    if (idx >= total) return;
    int i  = idx & 7;
    int g  = (idx >> 3) % G;
    int k8 = idx / (8*G);
    dst[idx] = (_Float16)src[g*srcK + koff + k8*8 + i];
}

__global__ void k_biaslang(const float* __restrict__ bil, const float* __restrict__ bhl,
                           float* __restrict__ biasL){
    int g = threadIdx.x;
    biasL[g] = bil[g] + bhl[g];
}

__global__ void k_fcbpad(const float* __restrict__ fcb_in, float* __restrict__ fcb){
    int i = blockIdx.x*256 + threadIdx.x;
    if (i >= NPAD) return;
    fcb[i] = (i < VOC) ? fcb_in[i] : -1e30f;
}

// fc_out_w -> bf16 MFMA B-fragment layout: [tile][khalf][lane][8]
__global__ void k_fragb(const float* __restrict__ fcw, unsigned short* __restrict__ fragB){
    int idx = blockIdx.x*256 + threadIdx.x;   // 126*2*64 = 16128
    int lane = idx & 63, kh = (idx>>6)&1, tile = idx>>7;
    int n = tile*16 + (lane & 15);
    int k = kh*32 + (lane >> 4)*8;
    unsigned short* d = fragB + (size_t)((tile*2+kh)*64 + lane)*8;
    #pragma unroll
    for (int i=0;i<8;++i)
        d[i] = (n < VOC) ? bf16r(fcw[n*64 + k + i]) : (unsigned short)0;
}

// ---------------------------------------------------------------- recurrent kernel

// acc[q] += sum_k x[k] * W[(q*64+j)][k], weights in f16 [k8][256][8] layout
__device__ __forceinline__ void gate_dot8(const _Float16* __restrict__ W,
                                          const _Float16* x, int j, float acc[4]){
    const h8* xp = (const h8*)x;
    #pragma unroll
    for (int k8=0;k8<8;++k8){
        h8 xv = xp[k8];
        #pragma unroll
        for (int q=0;q<4;++q){
            h8 wv = *(const h8*)(W + (size_t)(((k8<<8)+(q<<6)+j))*8);
            acc[q] = fdot2f(__builtin_shufflevector(xv,xv,0,1), __builtin_shufflevector(wv,wv,0,1), acc[q]);
            acc[q] = fdot2f(__builtin_shufflevector(xv,xv,2,3), __builtin_shufflevector(wv,wv,2,3), acc[q]);
            acc[q] = fdot2f(__builtin_shufflevector(xv,xv,4,5), __builtin_shufflevector(wv,wv,4,5), acc[q]);
            acc[q] = fdot2f(__builtin_shufflevector(xv,xv,6,7), __builtin_shufflevector(wv,wv,6,7), acc[q]);
        }
    }
}

__global__ __launch_bounds__(256) void k_recur(
    const int* __restrict__ inst, const float* __restrict__ embW,
    const float* __restrict__ diff, const float* __restrict__ prev,
    const float* __restrict__ pre1, const float* __restrict__ pre2,
    const _Float16* __restrict__ wAl, const _Float16* __restrict__ wAh,
    const _Float16* __restrict__ wLx, const _Float16* __restrict__ wLh,
    const _Float16* __restrict__ w1f1, const _Float16* __restrict__ w1f2,
    const float* __restrict__ a1w2, const float* __restrict__ a1b2,
    const float* __restrict__ a2w2, const float* __restrict__ a2b2,
    const float* __restrict__ tw1, const float* __restrict__ tb1,
    const float* __restrict__ tw2, const float* __restrict__ tb2,
    const float* __restrict__ biasL, unsigned short* __restrict__ h_hist)
{
    const int tid = threadIdx.x;
    const int r = tid >> 6;        // row within block (0..3)
    const int j = tid & 63;        // hidden unit
    const int rb = blockIdx.x*4 + r;

    __shared__ _Float16 hl16[4][64];   // h_lang (f16 broadcast copy)
    __shared__ _Float16 ha16[4][64];   // h_att
    __shared__ _Float16 tr16[4][64];   // trans output
    __shared__ float hpart[4][2][32];
    __shared__ float sbuf[4][2][25];
    __shared__ float att8s[4][8];
    __shared__ float ubuf[4][32];

    hl16[r][j] = (_Float16)0.f;
    ha16[r][j] = (_Float16)0.f;
    float c_att = 0.f, c_lang = 0.f;
    __syncthreads();

    for (int t = 0; t < NSTEP; ++t){
        int tok = inst[rb*TT + t];

        // ---- att LSTM gates: embW gather + h_lang·W_ih[:, :64] + h_att·W_hh
        float acc[4];
        {
            const float* eb = embW + tok*256;
            #pragma unroll
            for (int q=0;q<4;++q) acc[q] = eb[j + (q<<6)];
        }
        gate_dot8(wAl, &hl16[r][0], j, acc);
        gate_dot8(wAh, &ha16[r][0], j, acc);
        __syncthreads();                          // all reads of ha16 done
        {
            float ig = sigf(acc[0]), fg = sigf(acc[1]);
            float gg = tanh_(acc[2]), og = sigf(acc[3]);
            c_att = fg*c_att + ig*gg;
            float hA = og*tanh_(c_att);
            ha16[r][j] = (_Float16)hA;
        }
        __syncthreads();

        // ---- attention h-projection: lanes 0-31 attend1, 32-63 attend2
        {
            int half = j >> 5, jj = j & 31;
            const _Float16* wf = half ? w1f2 : w1f1;
            const h8* xp = (const h8*)&ha16[r][0];
            float hp = 0.f;
            #pragma unroll
            for (int k8=0;k8<8;++k8){
                h8 xv = xp[k8];
                h8 wv = *(const h8*)(wf + (size_t)(((k8<<5)+jj))*8);
                hp = fdot2f(__builtin_shufflevector(xv,xv,0,1), __builtin_shufflevector(wv,wv,0,1), hp);
                hp = fdot2f(__builtin_shufflevector(xv,xv,2,3), __builtin_shufflevector(wv,wv,2,3), hp);
                hp = fdot2f(__builtin_shufflevector(xv,xv,4,5), __builtin_shufflevector(wv,wv,4,5), hp);
                hp = fdot2f(__builtin_shufflevector(xv,xv,6,7), __builtin_shufflevector(wv,wv,6,7), hp);
            }
            hpart[r][half][jj] = hp;
        }
        __syncthreads();

        // ---- scores s[n] = b2 + sum_j relu(hpart[j]+pre[n][j])*w2[j]
        {
            int half = j >> 5, n = j & 31;
            if (n < NOBJ){
                const float* pre = half ? pre2 : pre1;
                const float4* pp = (const float4*)(pre + (size_t)(rb*NOBJ + n)*32);
                const float4* hh = (const float4*)&hpart[r][half][0];
                const float* w2 = half ? a2w2 : a1w2;
                float a = half ? a2b2[0] : a1b2[0];
                #pragma unroll
                for (int i=0;i<8;++i){
                    float4 pv = pp[i]; float4 hv = hh[i];
                    a += fmaxf(hv.x+pv.x,0.f)*w2[4*i+0] + fmaxf(hv.y+pv.y,0.f)*w2[4*i+1]
                       + fmaxf(hv.z+pv.z,0.f)*w2[4*i+2] + fmaxf(hv.w+pv.w,0.f)*w2[4*i+3];
                }
                sbuf[r][half][n] = a;
            }
        }
        __syncthreads();

        // ---- softmax over 25 + weighted sum of memory (8 lanes: 2 heads x 4 dims)
        if (j < 8){
            int half = j >> 2, d = j & 3;
            const float* mem = (half ? prev : diff) + (size_t)(rb*NOBJ)*4;
            const float* ss = &sbuf[r][half][0];
            float m = -1e30f;
            for (int n=0;n<NOBJ;++n) m = fmaxf(m, ss[n]);
            float s = 0.f, a = 0.f;
            for (int n=0;n<NOBJ;++n){ float e = __expf(ss[n]-m); s += e; a += e*mem[n*4+d]; }
            att8s[r][j] = a/s;
        }
        __syncthreads();

        // ---- trans MLP stage 1 (32 hidden)
        if (j < 32){
            float u = tb1[j];
            const float* w = tw1 + j*8;
            #pragma unroll
            for (int i=0;i<8;++i) u += att8s[r][i]*w[i];
            ubuf[r][j] = fmaxf(u, 0.f);
        }
        __syncthreads();
        // ---- trans stage 2 (64 out)
        {
            float tv = tb2[j];
            const float* w = tw2 + j*32;
            #pragma unroll
            for (int m=0;m<32;++m) tv += ubuf[r][m]*w[m];
            tr16[r][j] = (_Float16)tv;
        }
        __syncthreads();

        // ---- lang LSTM gates: [tr | h_att]·W_ih_lang + h_lang·W_hh_lang + bias
        #pragma unroll
        for (int q=0;q<4;++q) acc[q] = biasL[j + (q<<6)];
        gate_dot8(wLx,            &tr16[r][0], j, acc);
        gate_dot8(wLx + 8*256*8,  &ha16[r][0], j, acc);
        gate_dot8(wLh,            &hl16[r][0], j, acc);
        __syncthreads();                          // all reads of hl16 done
        {
            float ig = sigf(acc[0]), fg = sigf(acc[1]);
            float gg = tanh_(acc[2]), og = sigf(acc[3]);
            c_lang = fg*c_lang + ig*gg;
            float hL = og*tanh_(c_lang);
            hl16[r][j] = (_Float16)hL;
            h_hist[(size_t)(rb*NSTEP + t)*64 + j] = bf16r(hL);
        }
        __syncthreads();
    }
}

// ---------------------------------------------------------------- fc + log_softmax

// rows = b*47+t (16/block), cols = vocab (padded 2016). Two MFMA sweeps with
// online max/sum so logits never materialize.
__global__ __launch_bounds__(256) void k_fc(const unsigned short* __restrict__ h_hist,
                                            const unsigned short* __restrict__ fragB,
                                            const float* __restrict__ fcb,
                                            float* __restrict__ out)
{
    const int tid = threadIdx.x;
    const int w = tid >> 6, lane = tid & 63;
    const int q = lane >> 4, l16 = lane & 15;
    const int rowbase = blockIdx.x*16;

    // A fragments: A[m=l16][k=q*8+i], two K-halves
    const short8 a0 = *(const short8*)(h_hist + (size_t)(rowbase + l16)*64 + q*8);
    const short8 a1 = *(const short8*)(h_hist + (size_t)(rowbase + l16)*64 + 32 + q*8);

    float m[4], s[4];
    #pragma unroll
    for (int i=0;i<4;++i){ m[i] = -INFINITY; s[i] = 0.f; }

    for (int tile = w; tile < NTILE; tile += 4){
        const short8 b0 = *(const short8*)(fragB + (size_t)((tile*2+0)*64 + lane)*8);
        const short8 b1 = *(const short8*)(fragB + (size_t)((tile*2+1)*64 + lane)*8);
        f32x4 acc = {0.f,0.f,0.f,0.f};
        acc = __builtin_amdgcn_mfma_f32_16x16x32_bf16(a0, b0, acc, 0, 0, 0);
        acc = __builtin_amdgcn_mfma_f32_16x16x32_bf16(a1, b1, acc, 0, 0, 0);
        float bias = fcb[tile*16 + l16];
        #pragma unroll
        for (int i=0;i<4;++i){
            float v = acc[i] + bias;
            float nm = fmaxf(m[i], v);
            s[i] = s[i]*__expf(m[i]-nm) + __expf(v-nm);
            m[i] = nm;
        }
    }
    // combine across the 16 col-lanes within each quad
    #pragma unroll
    for (int i=0;i<4;++i){
        #pragma unroll
        for (int off=1; off<16; off<<=1){
            float om = __shfl_xor(m[i], off, 64);
            float os = __shfl_xor(s[i], off, 64);
            float nm = fmaxf(m[i], om);
            s[i] = s[i]*__expf(m[i]-nm) + os*__expf(om-nm);
            m[i] = nm;
        }
    }
    __shared__ float lm[4][16], ls[4][16], fm[16], fl[16];
    if (l16 == 0){
        #pragma unroll
        for (int i=0;i<4;++i){ lm[w][q*4+i] = m[i]; ls[w][q*4+i] = s[i]; }
    }
    __syncthreads();
    if (tid < 16){
        float M = -INFINITY, S = 0.f;
        #pragma unroll
        for (int ww=0;ww<4;++ww){
            float om = lm[ww][tid], os = ls[ww][tid];
            float nm = fmaxf(M, om);
            S = S*__expf(M-nm) + os*__expf(om-nm);
            M = nm;
        }
        fm[tid] = M; fl[tid] = __logf(S);
    }
    __syncthreads();
    float Mr[4], Lr[4];
    #pragma unroll
    for (int i=0;i<4;++i){ Mr[i] = fm[q*4+i]; Lr[i] = fl[q*4+i]; }

    // sweep 2: recompute logits, write logp
    for (int tile = w; tile < NTILE; tile += 4){
        const short8 b0 = *(const short8*)(fragB + (size_t)((tile*2+0)*64 + lane)*8);
        const short8 b1 = *(const short8*)(fragB + (size_t)((tile*2+1)*64 + lane)*8);
        f32x4 acc = {0.f,0.f,0.f,0.f};
        acc = __builtin_amdgcn_mfma_f32_16x16x32_bf16(a0, b0, acc, 0, 0, 0);
        acc = __builtin_amdgcn_mfma_f32_16x16x32_bf16(a1, b1, acc, 0, 0, 0);
        int col = tile*16 + l16;
        if (col < VOC){
            float bias = fcb[col];
            #pragma unroll
            for (int i=0;i<4;++i)
                out[(size_t)(rowbase + q*4 + i)*VOC + col] = acc[i] + bias - Mr[i] - Lr[i];
        }
    }
}

// ---------------------------------------------------------------- launcher

extern "C" void kernel_launch(void* const* d_in, const int* in_sizes, int n_in,
                              void* d_out, int out_size, void* d_ws, size_t ws_size,
                              hipStream_t stream)
{
    const int*   inst  = (const int*)  d_in[0];
    const float* prev  = (const float*)d_in[1];
    const float* fin   = (const float*)d_in[2];
    const float* embed = (const float*)d_in[3];
    const float* Wia   = (const float*)d_in[4];
    const float* bia   = (const float*)d_in[6];
    const float* bha   = (const float*)d_in[7];
    const float* Wil   = (const float*)d_in[8];
    const float* Whl   = (const float*)d_in[9];
    const float* bil   = (const float*)d_in[10];
    const float* bhl   = (const float*)d_in[11];
    const float* Wha   = (const float*)d_in[5];
    const float* fcw   = (const float*)d_in[12];
    const float* fcbi  = (const float*)d_in[13];
    const float* a1w1  = (const float*)d_in[14];
    const float* a1b1  = (const float*)d_in[15];
    const float* a1w2  = (const float*)d_in[16];
    const float* a1b2  = (const float*)d_in[17];
    const float* a2w1  = (const float*)d_in[18];
    const float* a2b1  = (const float*)d_in[19];
    const float* a2w2  = (const float*)d_in[20];
    const float* a2b2  = (const float*)d_in[21];
    const float* tw1   = (const float*)d_in[22];
    const float* tb1   = (const float*)d_in[23];
    const float* tw2   = (const float*)d_in[24];
    const float* tb2   = (const float*)d_in[25];
    float* out = (float*)d_out;

    char* wsb = (char*)d_ws; size_t off = 0;
    auto alloc = [&](size_t bytes)->char*{
        char* p = wsb + off; off = (off + bytes + 511) & ~(size_t)511; return p;
    };
    float*          embW  = (float*)alloc((size_t)VOC*256*4);
    float*          diff  = (float*)alloc((size_t)BATCH*NOBJ*4*4);
    float*          pre1  = (float*)alloc((size_t)BATCH*NOBJ*32*4);
    float*          pre2  = (float*)alloc((size_t)BATCH*NOBJ*32*4);
    _Float16*       wAl   = (_Float16*)alloc((size_t)64*256*2);
    _Float16*       wAh   = (_Float16*)alloc((size_t)64*256*2);
    _Float16*       wLx   = (_Float16*)alloc((size_t)128*256*2);
    _Float16*       wLh   = (_Float16*)alloc((size_t)64*256*2);
    _Float16*       w1f1  = (_Float16*)alloc((size_t)64*32*2);
    _Float16*       w1f2  = (_Float16*)alloc((size_t)64*32*2);
    float*          biasL = (float*)alloc(256*4);
    float*          fcb   = (float*)alloc((size_t)NPAD*4);
    unsigned short* hhist = (unsigned short*)alloc((size_t)NROWS*64*2);
    unsigned short* fragB = (unsigned short*)alloc((size_t)NTILE*2*64*8*2);

    // prep
    k_pre   <<<(BATCH*NOBJ+255)/256, 256, 0, stream>>>(prev, fin, a1w1, a1b1, a2w1, a2b1, diff, pre1, pre2);
    k_embw  <<<VOC, 256, 0, stream>>>(embed, Wia, bia, bha, embW);
    k_packw <<<64,  256, 0, stream>>>(Wia, wAl,  256, 128, 0, 64*256);   // W_ih_att cols 0..63  (h_lang)
    k_packw <<<64,  256, 0, stream>>>(Wha, wAh,  256,  64, 0, 64*256);   // W_hh_att             (h_att)
    k_packw <<<128, 256, 0, stream>>>(Wil, wLx,  256, 128, 0, 128*256);  // W_ih_lang full [tr|h_att]
    k_packw <<<64,  256, 0, stream>>>(Whl, wLh,  256,  64, 0, 64*256);   // W_hh_lang            (h_lang)
    k_packw <<<8,   256, 0, stream>>>(a1w1, w1f1, 32,  68, 0, 64*32);    // att1 w1 cols 0..63
    k_packw <<<8,   256, 0, stream>>>(a2w1, w1f2, 32,  68, 0, 64*32);    // att2 w1 cols 0..63
    k_biaslang<<<1, 256, 0, stream>>>(bil, bhl, biasL);
    k_fcbpad  <<<(NPAD+255)/256, 256, 0, stream>>>(fcbi, fcb);
    k_fragb   <<<63, 256, 0, stream>>>(fcw, fragB);

    // recurrent scan: 256 blocks x 4 batch rows, writes bf16 h_lang history
    k_recur<<<BATCH/4, 256, 0, stream>>>(inst, embW, diff, prev, pre1, pre2,
                                         wAl, wAh, wLx, wLh, w1f1, w1f2,
                                         a1w2, a1b2, a2w2, a2b2,
                                         tw1, tb1, tw2, tb2, biasL, hhist);

    // big projection + log_softmax
    k_fc<<<NROWS/16, 256, 0, stream>>>(hhist, fragB, fcb, out);
}

// Round 2
// 865.211 us; speedup vs baseline: 1.9790x; 1.9790x over previous
//
#include <hip/hip_runtime.h>

// Problem constants
#define BATCH 1024
#define TT 48          // inst columns
#define NSTEP 47       // scan steps
#define VOC 2001       // V+1
#define RNN 64
#define NOBJ 25
#define NROWS (BATCH*NSTEP)   // 48128
#define NTILE 126             // ceil(2016/16)
#define NPAD 2016

typedef _Float16 h2 __attribute__((ext_vector_type(2)));
typedef _Float16 h8 __attribute__((ext_vector_type(8)));
typedef short short8 __attribute__((ext_vector_type(8)));
typedef float f32x4 __attribute__((ext_vector_type(4)));

__device__ __forceinline__ float fdot2f(h2 a, h2 b, float c){
#if __has_builtin(__builtin_amdgcn_fdot2)
    return __builtin_amdgcn_fdot2(a, b, c, false);
#else
    return c + (float)a[0]*(float)b[0] + (float)a[1]*(float)b[1];
#endif
}

__device__ __forceinline__ float dot8(h8 w, h8 x, float acc){
    acc = fdot2f(__builtin_shufflevector(w,w,0,1), __builtin_shufflevector(x,x,0,1), acc);
    acc = fdot2f(__builtin_shufflevector(w,w,2,3), __builtin_shufflevector(x,x,2,3), acc);
    acc = fdot2f(__builtin_shufflevector(w,w,4,5), __builtin_shufflevector(x,x,4,5), acc);
    acc = fdot2f(__builtin_shufflevector(w,w,6,7), __builtin_shufflevector(x,x,6,7), acc);
    return acc;
}

__device__ __forceinline__ float sigf(float x){ return 1.f/(1.f+__expf(-x)); }
__device__ __forceinline__ float tanh_(float x){
    float e = __expf(2.f*fminf(x, 15.f));   // clamp avoids inf/inf NaN
    return (e-1.f)/(e+1.f);
}
__device__ __forceinline__ unsigned short bf16r(float f){
    unsigned u = __float_as_uint(f);
    return (unsigned short)((u + 0x7FFFu + ((u>>16)&1u)) >> 16);
}

// ---------------------------------------------------------------- prep kernels

// diff_canvas + time-invariant attention terms pre1/pre2 [B,25,32]
__global__ void k_pre(const float* __restrict__ prev, const float* __restrict__ fin,
                      const float* __restrict__ a1w1, const float* __restrict__ a1b1,
                      const float* __restrict__ a2w1, const float* __restrict__ a2b1,
                      float* __restrict__ diff, float* __restrict__ pre1, float* __restrict__ pre2){
    int idx = blockIdx.x*256 + threadIdx.x;
    if (idx >= BATCH*NOBJ) return;
    float p0 = prev[idx*4+0], p1 = prev[idx*4+1], p2 = prev[idx*4+2], p3 = prev[idx*4+3];
    bool masked = (p0+p1+p2+p3) > 0.f;
    float d0 = masked ? -1.f : fin[idx*4+0];
    float d1 = masked ? -1.f : fin[idx*4+1];
    float d2 = masked ? -1.f : fin[idx*4+2];
    float d3 = masked ? -1.f : fin[idx*4+3];
    diff[idx*4+0]=d0; diff[idx*4+1]=d1; diff[idx*4+2]=d2; diff[idx*4+3]=d3;
    for (int j=0;j<32;++j){
        const float* w1 = a1w1 + j*68 + 64;
        const float* w2 = a2w1 + j*68 + 64;
        pre1[idx*32+j] = a1b1[j] + d0*w1[0] + d1*w1[1] + d2*w1[2] + d3*w1[3];
        pre2[idx*32+j] = a2b1[j] + p0*w2[0] + p1*w2[1] + p2*w2[2] + p3*w2[3];
    }
}

// embW[v][g] = b_ih_att[g]+b_hh_att[g] + sum_k embed[v][k]*W_ih_att[g][64+k]
__global__ void k_embw(const float* __restrict__ embed, const float* __restrict__ Wia,
                       const float* __restrict__ bia, const float* __restrict__ bha,
                       float* __restrict__ embW){
    int v = blockIdx.x, g = threadIdx.x;
    __shared__ float er[64];
    if (g < 64) er[g] = embed[v*64+g];
    __syncthreads();
    float acc = bia[g] + bha[g];
    const float* wr = Wia + g*128 + 64;
    #pragma unroll 8
    for (int k=0;k<64;++k) acc += er[k]*wr[k];
    embW[v*256+g] = acc;
}

// pack fp32 weight rows [G][srcK] cols koff..koff+K-1 -> f16 row-major [G][K]
__global__ void k_packrow(const float* __restrict__ src, _Float16* __restrict__ dst,
                          int srcK, int koff, int K, int total){
    int idx = blockIdx.x*256 + threadIdx.x;
    if (idx >= total) return;
    int k = idx % K, g = idx / K;
    dst[idx] = (_Float16)src[g*srcK + koff + k];
}

// Weff[g][m] = sum_d W_ih_lang[g][d]*tw2[d][m]; biasL2[g] = bil+bhl+sum_d W[g][d]*tb2[d]
__global__ void k_weff(const float* __restrict__ Wil, const float* __restrict__ tw2,
                       const float* __restrict__ tb2, const float* __restrict__ bil,
                       const float* __restrict__ bhl, _Float16* __restrict__ Weff,
                       float* __restrict__ biasL2){
    __shared__ float t2[64*32];
    int g = threadIdx.x;
    for (int i=g;i<2048;i+=256) t2[i] = tw2[i];
    __syncthreads();
    float accs[32];
    #pragma unroll
    for (int m=0;m<32;++m) accs[m]=0.f;
    float bf = bil[g] + bhl[g];
    for (int d=0;d<64;++d){
        float w = Wil[g*128 + d];
        bf += w * tb2[d];
        #pragma unroll
        for (int m=0;m<32;++m) accs[m] += w * t2[d*32+m];
    }
    #pragma unroll
    for (int m=0;m<32;++m) Weff[g*32+m] = (_Float16)accs[m];
    biasL2[g] = bf;
}

__global__ void k_fcbpad(const float* __restrict__ fcb_in, float* __restrict__ fcb){
    int i = blockIdx.x*256 + threadIdx.x;
    if (i >= NPAD) return;
    fcb[i] = (i < VOC) ? fcb_in[i] : -1e30f;
}

// fc_out_w -> bf16 MFMA B-fragment layout: [tile][khalf][lane][8]
__global__ void k_fragb(const float* __restrict__ fcw, unsigned short* __restrict__ fragB){
    int idx = blockIdx.x*256 + threadIdx.x;   // 126*2*64 = 16128
    int lane = idx & 63, kh = (idx>>6)&1, tile = idx>>7;
    int n = tile*16 + (lane & 15);
    int k = kh*32 + (lane >> 4)*8;
    unsigned short* d = fragB + (size_t)((tile*2+kh)*64 + lane)*8;
    #pragma unroll
    for (int i=0;i<8;++i)
        d[i] = (n < VOC) ? bf16r(fcw[n*64 + k + i]) : (unsigned short)0;
}

// ---------------------------------------------------------------- recurrent kernel
// 1 batch row per block, 256 threads. Thread (g=tid>>6, j=tid&63) owns its
// gate-row weights in VGPRs; activations broadcast from LDS. Inner loop has
// zero global reads except the 1KB/step embW gather.

__global__ __launch_bounds__(256, 2) void k_recur(
    const int* __restrict__ inst, const float* __restrict__ embW,
    const float* __restrict__ diff, const float* __restrict__ prev,
    const float* __restrict__ pre1, const float* __restrict__ pre2,
    const _Float16* __restrict__ attLp, const _Float16* __restrict__ attHp,
    const _Float16* __restrict__ wLhap, const _Float16* __restrict__ wLhlp,
    const _Float16* __restrict__ Weffp, const float* __restrict__ biasL2,
    const _Float16* __restrict__ w1fp,
    const float* __restrict__ a1w2, const float* __restrict__ a1b2,
    const float* __restrict__ a2w2, const float* __restrict__ a2b2,
    const float* __restrict__ tw1, const float* __restrict__ tb1,
    unsigned short* __restrict__ h_hist)
{
    const int tid = threadIdx.x;
    const int rb  = blockIdx.x;

    __shared__ float gbuf[256];
    __shared__ __align__(16) _Float16 hl16[64];
    __shared__ __align__(16) _Float16 ha16[64];
    __shared__ __align__(16) _Float16 u16[32];
    __shared__ float hpart[64];
    __shared__ float sbuf[2][32];
    __shared__ float att8s[8];
    __shared__ __align__(16) float preS[2][25][36];   // stride 36: bank spread
    __shared__ float memS[2*25*4];
    __shared__ __align__(16) _Float16 w1fS[64*72];    // stride 72 f16: bank spread
    __shared__ float tw1S[256], tb1S[32], w2S[2][32], b2S[2];
    __shared__ int   tokS[NSTEP];
    __shared__ float biasS[256];

    // ---- one-time block init
    for (int i=tid;i<NSTEP;i+=256) tokS[i] = inst[rb*TT + i];
    for (int i=tid;i<1600;i+=256){
        int h = i/800, rem = i - h*800, n = rem>>5, k = rem&31;
        preS[h][n][k] = (h ? pre2 : pre1)[(size_t)(rb*NOBJ+n)*32 + k];
    }
    for (int i=tid;i<200;i+=256)
        memS[i] = (i<100 ? diff : prev)[(size_t)rb*100 + (i%100)];
    for (int i=tid;i<4096;i+=256){
        int r = i>>6, k = i&63;
        w1fS[r*72+k] = w1fp[i];
    }
    if (tid<256) tw1S[tid] = tw1[tid];
    if (tid<32)  tb1S[tid] = tb1[tid];
    if (tid<64)  w2S[tid>>5][tid&31] = (tid<32 ? a1w2 : a2w2)[tid&31];
    if (tid<2)   b2S[tid] = tid ? a2b2[0] : a1b2[0];
    biasS[tid] = biasL2[tid];
    if (tid<64){ hl16[tid]=(_Float16)0.f; ha16[tid]=(_Float16)0.f; }

    // ---- weight registers (row = tid of each matrix)
    h8 wAL[8], wAH[8], wLHa[8], wLHl[8], wEf[4];
    {
        const h8* p0 = (const h8*)(attLp + (size_t)tid*64);
        const h8* p1 = (const h8*)(attHp + (size_t)tid*64);
        const h8* p2 = (const h8*)(wLhap + (size_t)tid*64);
        const h8* p3 = (const h8*)(wLhlp + (size_t)tid*64);
        const h8* p4 = (const h8*)(Weffp + (size_t)tid*32);
        #pragma unroll
        for (int k=0;k<8;++k){ wAL[k]=p0[k]; wAH[k]=p1[k]; wLHa[k]=p2[k]; wLHl[k]=p3[k]; }
        #pragma unroll
        for (int k=0;k<4;++k) wEf[k]=p4[k];
    }
    float c_att = 0.f, c_lang = 0.f;
    __syncthreads();

    const int wave = tid>>6, lane = tid&63;

    for (int t=0;t<NSTEP;++t){
        // ---- att LSTM gates
        float acc = embW[(size_t)tokS[t]*256 + tid];
        {
            const h8* xh = (const h8*)hl16;
            const h8* xa = (const h8*)ha16;
            #pragma unroll
            for (int k=0;k<8;++k) acc = dot8(wAL[k], xh[k], acc);
            #pragma unroll
            for (int k=0;k<8;++k) acc = dot8(wAH[k], xa[k], acc);
        }
        gbuf[tid] = acc;
        __syncthreads();                                     // 1
        if (tid < 64){
            float i_=sigf(gbuf[tid]), f_=sigf(gbuf[64+tid]);
            float g_=tanh_(gbuf[128+tid]), o_=sigf(gbuf[192+tid]);
            c_att = f_*c_att + i_*g_;
            ha16[tid] = (_Float16)(o_*tanh_(c_att));
        }
        __syncthreads();                                     // 2

        // ---- attention h-projection (wave 1): 64 units, weights from LDS
        if (wave==1){
            const h8* xa = (const h8*)ha16;
            const h8* wr = (const h8*)&w1fS[lane*72];
            float hp = 0.f;
            #pragma unroll
            for (int k=0;k<8;++k) hp = dot8(wr[k], xa[k], hp);
            hpart[lane] = hp;
        }
        __syncthreads();                                     // 3

        // ---- scores (wave 2): 2 heads x 25 objects
        if (wave==2){
            int half = lane>>5, n = lane&31;
            if (n < NOBJ){
                const float4* pp = (const float4*)&preS[half][n][0];
                const float*  hp = &hpart[half*32];
                const float*  w2 = &w2S[half][0];
                float a = b2S[half];
                #pragma unroll
                for (int i=0;i<8;++i){
                    float4 pv = pp[i];
                    a += fmaxf(hp[4*i+0]+pv.x,0.f)*w2[4*i+0]
                       + fmaxf(hp[4*i+1]+pv.y,0.f)*w2[4*i+1]
                       + fmaxf(hp[4*i+2]+pv.z,0.f)*w2[4*i+2]
                       + fmaxf(hp[4*i+3]+pv.w,0.f)*w2[4*i+3];
                }
                sbuf[half][n] = a;
            }
        }
        __syncthreads();                                     // 4

        // ---- softmax over 25 + weighted memory sum (8 lanes of wave 3)
        if (tid>=192 && tid<200){
            int j = tid-192, half = j>>2, d = j&3;
            const float* ss = &sbuf[half][0];
            const float* mem = &memS[half*100];
            float m = -1e30f;
            for (int n=0;n<NOBJ;++n) m = fmaxf(m, ss[n]);
            float s=0.f, a=0.f;
            for (int n=0;n<NOBJ;++n){ float e=__expf(ss[n]-m); s+=e; a+=e*mem[n*4+d]; }
            att8s[j] = a/s;
        }
        __syncthreads();                                     // 5

        // ---- trans stage 1 (32 lanes of wave 0)
        if (tid < 32){
            float u = tb1S[tid];
            #pragma unroll
            for (int i=0;i<8;++i) u += att8s[i]*tw1S[tid*8+i];
            u16[tid] = (_Float16)fmaxf(u, 0.f);
        }
        __syncthreads();                                     // 6

        // ---- lang LSTM gates (tw2 folded into Weff)
        float acc2 = biasS[tid];
        {
            const h8* xu = (const h8*)u16;
            const h8* xa = (const h8*)ha16;
            const h8* xh = (const h8*)hl16;
            #pragma unroll
            for (int k=0;k<4;++k) acc2 = dot8(wEf[k], xu[k], acc2);
            #pragma unroll
            for (int k=0;k<8;++k) acc2 = dot8(wLHa[k], xa[k], acc2);
            #pragma unroll
            for (int k=0;k<8;++k) acc2 = dot8(wLHl[k], xh[k], acc2);
        }
        gbuf[tid] = acc2;
        __syncthreads();                                     // 7
        if (tid < 64){
            float i_=sigf(gbuf[tid]), f_=sigf(gbuf[64+tid]);
            float g_=tanh_(gbuf[128+tid]), o_=sigf(gbuf[192+tid]);
            c_lang = f_*c_lang + i_*g_;
            float hL = o_*tanh_(c_lang);
            hl16[tid] = (_Float16)hL;
            h_hist[((size_t)rb*NSTEP + t)*64 + tid] = bf16r(hL);
        }
        __syncthreads();                                     // 8
    }
}

// ---------------------------------------------------------------- fc + log_softmax

__global__ __launch_bounds__(256) void k_fc(const unsigned short* __restrict__ h_hist,
                                            const unsigned short* __restrict__ fragB,
                                            const float* __restrict__ fcb,
                                            float* __restrict__ out)
{
    const int tid = threadIdx.x;
    const int w = tid >> 6, lane = tid & 63;
    const int q = lane >> 4, l16 = lane & 15;
    const int rowbase = blockIdx.x*16;

    const short8 a0 = *(const short8*)(h_hist + (size_t)(rowbase + l16)*64 + q*8);
    const short8 a1 = *(const short8*)(h_hist + (size_t)(rowbase + l16)*64 + 32 + q*8);

    float m[4], s[4];
    #pragma unroll
    for (int i=0;i<4;++i){ m[i] = -INFINITY; s[i] = 0.f; }

    for (int tile = w; tile < NTILE; tile += 4){
        const short8 b0 = *(const short8*)(fragB + (size_t)((tile*2+0)*64 + lane)*8);
        const short8 b1 = *(const short8*)(fragB + (size_t)((tile*2+1)*64 + lane)*8);
        f32x4 acc = {0.f,0.f,0.f,0.f};
        acc = __builtin_amdgcn_mfma_f32_16x16x32_bf16(a0, b0, acc, 0, 0, 0);
        acc = __builtin_amdgcn_mfma_f32_16x16x32_bf16(a1, b1, acc, 0, 0, 0);
        float bias = fcb[tile*16 + l16];
        #pragma unroll
        for (int i=0;i<4;++i){
            float v = acc[i] + bias;
            float nm = fmaxf(m[i], v);
            s[i] = s[i]*__expf(m[i]-nm) + __expf(v-nm);
            m[i] = nm;
        }
    }
    #pragma unroll
    for (int i=0;i<4;++i){
        #pragma unroll
        for (int off=1; off<16; off<<=1){
            float om = __shfl_xor(m[i], off, 64);
            float os = __shfl_xor(s[i], off, 64);
            float nm = fmaxf(m[i], om);
            s[i] = s[i]*__expf(m[i]-nm) + os*__expf(om-nm);
            m[i] = nm;
        }
    }
    __shared__ float lm[4][16], ls[4][16], fm[16], fl[16];
    if (l16 == 0){
        #pragma unroll
        for (int i=0;i<4;++i){ lm[w][q*4+i] = m[i]; ls[w][q*4+i] = s[i]; }
    }
    __syncthreads();
    if (tid < 16){
        float M = -INFINITY, S = 0.f;
        #pragma unroll
        for (int ww=0;ww<4;++ww){
            float om = lm[ww][tid], os = ls[ww][tid];
            float nm = fmaxf(M, om);
            S = S*__expf(M-nm) + os*__expf(om-nm);
            M = nm;
        }
        fm[tid] = M; fl[tid] = __logf(S);
    }
    __syncthreads();
    float Mr[4], Lr[4];
    #pragma unroll
    for (int i=0;i<4;++i){ Mr[i] = fm[q*4+i]; Lr[i] = fl[q*4+i]; }

    for (int tile = w; tile < NTILE; tile += 4){
        const short8 b0 = *(const short8*)(fragB + (size_t)((tile*2+0)*64 + lane)*8);
        const short8 b1 = *(const short8*)(fragB + (size_t)((tile*2+1)*64 + lane)*8);
        f32x4 acc = {0.f,0.f,0.f,0.f};
        acc = __builtin_amdgcn_mfma_f32_16x16x32_bf16(a0, b0, acc, 0, 0, 0);
        acc = __builtin_amdgcn_mfma_f32_16x16x32_bf16(a1, b1, acc, 0, 0, 0);
        int col = tile*16 + l16;
        if (col < VOC){
            float bias = fcb[col];
            #pragma unroll
            for (int i=0;i<4;++i)
                out[(size_t)(rowbase + q*4 + i)*VOC + col] = acc[i] + bias - Mr[i] - Lr[i];
        }
    }
}

// ---------------------------------------------------------------- launcher

extern "C" void kernel_launch(void* const* d_in, const int* in_sizes, int n_in,
                              void* d_out, int out_size, void* d_ws, size_t ws_size,
                              hipStream_t stream)
{
    const int*   inst  = (const int*)  d_in[0];
    const float* prev  = (const float*)d_in[1];
    const float* fin   = (const float*)d_in[2];
    const float* embed = (const float*)d_in[3];
    const float* Wia   = (const float*)d_in[4];
    const float* Wha   = (const float*)d_in[5];
    const float* bia   = (const float*)d_in[6];
    const float* bha   = (const float*)d_in[7];
    const float* Wil   = (const float*)d_in[8];
    const float* Whl   = (const float*)d_in[9];
    const float* bil   = (const float*)d_in[10];
    const float* bhl   = (const float*)d_in[11];
    const float* fcw   = (const float*)d_in[12];
    const float* fcbi  = (const float*)d_in[13];
    const float* a1w1  = (const float*)d_in[14];
    const float* a1b1  = (const float*)d_in[15];
    const float* a1w2  = (const float*)d_in[16];
    const float* a1b2  = (const float*)d_in[17];
    const float* a2w1  = (const float*)d_in[18];
    const float* a2b1  = (const float*)d_in[19];
    const float* a2w2  = (const float*)d_in[20];
    const float* a2b2  = (const float*)d_in[21];
    const float* tw1   = (const float*)d_in[22];
    const float* tb1   = (const float*)d_in[23];
    const float* tw2   = (const float*)d_in[24];
    const float* tb2   = (const float*)d_in[25];
    float* out = (float*)d_out;

    char* wsb = (char*)d_ws; size_t off = 0;
    auto alloc = [&](size_t bytes)->char*{
        char* p = wsb + off; off = (off + bytes + 511) & ~(size_t)511; return p;
    };
    float*          embW  = (float*)alloc((size_t)VOC*256*4);
    float*          diff  = (float*)alloc((size_t)BATCH*NOBJ*4*4);
    float*          pre1  = (float*)alloc((size_t)BATCH*NOBJ*32*4);
    float*          pre2  = (float*)alloc((size_t)BATCH*NOBJ*32*4);
    _Float16*       attLp = (_Float16*)alloc((size_t)256*64*2);
    _Float16*       attHp = (_Float16*)alloc((size_t)256*64*2);
    _Float16*       wLhap = (_Float16*)alloc((size_t)256*64*2);
    _Float16*       wLhlp = (_Float16*)alloc((size_t)256*64*2);
    _Float16*       Weffp = (_Float16*)alloc((size_t)256*32*2);
    _Float16*       w1fp  = (_Float16*)alloc((size_t)64*64*2);
    float*          biasL2= (float*)alloc(256*4);
    float*          fcb   = (float*)alloc((size_t)NPAD*4);
    unsigned short* hhist = (unsigned short*)alloc((size_t)NROWS*64*2);
    unsigned short* fragB = (unsigned short*)alloc((size_t)NTILE*2*64*8*2);

    // prep
    k_pre    <<<(BATCH*NOBJ+255)/256, 256, 0, stream>>>(prev, fin, a1w1, a1b1, a2w1, a2b1, diff, pre1, pre2);
    k_embw   <<<VOC, 256, 0, stream>>>(embed, Wia, bia, bha, embW);
    k_packrow<<<64, 256, 0, stream>>>(Wia, attLp, 128, 0,  64, 256*64);   // W_ih_att[:, :64]  (h_lang)
    k_packrow<<<64, 256, 0, stream>>>(Wha, attHp,  64, 0,  64, 256*64);   // W_hh_att          (h_att)
    k_packrow<<<64, 256, 0, stream>>>(Wil, wLhap, 128, 64, 64, 256*64);   // W_ih_lang[:,64:]  (h_att)
    k_packrow<<<64, 256, 0, stream>>>(Whl, wLhlp,  64, 0,  64, 256*64);   // W_hh_lang         (h_lang)
    k_packrow<<<8,  256, 0, stream>>>(a1w1, w1fp,       68, 0, 64, 32*64);// att1 w1[:, :64]
    k_packrow<<<8,  256, 0, stream>>>(a2w1, w1fp+32*64, 68, 0, 64, 32*64);// att2 w1[:, :64]
    k_weff   <<<1, 256, 0, stream>>>(Wil, tw2, tb2, bil, bhl, Weffp, biasL2);
    k_fcbpad <<<(NPAD+255)/256, 256, 0, stream>>>(fcbi, fcb);
    k_fragb  <<<63, 256, 0, stream>>>(fcw, fragB);

    // recurrent scan: 1 batch row per block
    k_recur<<<BATCH, 256, 0, stream>>>(inst, embW, diff, prev, pre1, pre2,
                                       attLp, attHp, wLhap, wLhlp, Weffp, biasL2, w1fp,
                                       a1w2, a1b2, a2w2, a2b2, tw1, tb1, hhist);

    // big projection + log_softmax
    k_fc<<<NROWS/16, 256, 0, stream>>>(hhist, fragB, fcb, out);
}